// Round 12
// baseline (2049.259 us; speedup 1.0000x reference)
//
#include <hip/hip_runtime.h>
#include <float.h>
#include <math.h>

#define MG 128
#define NNODE 62
#define DD 512
#define NH 8
#define DH 64
#define DFF 2048
#define NLAYER 4
#define EPG 600
#define KP1 50
#define KP2 40
#define NTOK (MG*NNODE)      // 7936
#define NEDGE (MG*EPG)       // 76800
#define EPSV 1e-5f
#define PW 68                // padded fp32 LDS row width for attn

typedef unsigned short u16;
using bf16x8 = __attribute__((ext_vector_type(8))) short;
using f32x4  = __attribute__((ext_vector_type(4))) float;

__device__ __forceinline__ float wave_sum(float v) {
  for (int off = 32; off; off >>= 1) v += __shfl_xor(v, off);
  return v;
}
__device__ __forceinline__ float wave_max(float v) {
  for (int off = 32; off; off >>= 1) v = fmaxf(v, __shfl_xor(v, off));
  return v;
}
__device__ __forceinline__ u16 f2b(float x) {
  union { float f; unsigned u; } v; v.f = x;
  unsigned r = v.u + 0x7fffu + ((v.u >> 16) & 1u);
  return (u16)(r >> 16);
}
__device__ __forceinline__ float b2f(u16 h) {
  union { float f; unsigned u; } v; v.u = ((unsigned)h) << 16;
  return v.f;
}
__device__ __forceinline__ void f2bsplit(float x, u16& h, u16& l) {
  h = f2b(x);
  l = f2b(x - b2f(h));
}
__device__ __forceinline__ void load_lds16(const u16* g, u16* l) {
  __builtin_amdgcn_global_load_lds(
      (const __attribute__((address_space(1))) unsigned int*)(const void*)g,
      (__attribute__((address_space(3))) unsigned int*)(void*)l, 16, 0, 0);
}
__device__ __forceinline__ void cvt8(const float* __restrict__ p, bf16x8& vh, bf16x8& vl) {
  #pragma unroll
  for (int e = 0; e < 8; ++e) {
    u16 h, l; f2bsplit(p[e], h, l);
    vh[e] = (short)h; vl[e] = (short)l;
  }
}
__device__ __forceinline__ void cvt8s(const float* __restrict__ p, bf16x8& vh, bf16x8& vl) {
  #pragma unroll
  for (int e = 0; e < 8; ++e) {
    u16 h, l; f2bsplit(p[e*PW], h, l);
    vh[e] = (short)h; vl[e] = (short)l;
  }
}

// ---------------- BatchNorm stats ----------------
__global__ __launch_bounds__(256) void bn_stats_kernel(const float* __restrict__ x,
    float* __restrict__ mu, float* __restrict__ rs) {
  int s = blockIdx.x;
  float sum = 0.f, sq = 0.f;
  for (int i = threadIdx.x; i < MG*NNODE; i += 256) {
    int b = i / NNODE, j = i - b*NNODE;
    float v = x[(size_t)(b*NNODE + s)*NNODE + j];
    sum += v; sq += v*v;
  }
  __shared__ float r1[4], r2[4];
  sum = wave_sum(sum); sq = wave_sum(sq);
  int wv = threadIdx.x >> 6, lane = threadIdx.x & 63;
  if (lane == 0) { r1[wv] = sum; r2[wv] = sq; }
  __syncthreads();
  if (threadIdx.x == 0) {
    float S = r1[0]+r1[1]+r1[2]+r1[3];
    float Q = r2[0]+r2[1]+r2[2]+r2[3];
    float m = S / (float)(MG*NNODE);
    float var = Q / (float)(MG*NNODE) - m*m;
    mu[s] = m;
    rs[s] = rsqrtf(var + EPSV);
  }
}

// ---------------- embed: split-bf16 only ----------------
__global__ __launch_bounds__(256) void embed_kernel(const float* __restrict__ x,
    const float* __restrict__ mu, const float* __restrict__ rs,
    const float* __restrict__ gg, const float* __restrict__ bb,
    const float* __restrict__ W,
    u16* __restrict__ Th, u16* __restrict__ Tl) {
  int tok = blockIdx.x;
  int s = tok >> 7, b = tok & 127;
  __shared__ float xb[NNODE];
  if (threadIdx.x < NNODE) {
    float v = x[(size_t)(b*NNODE + s)*NNODE + threadIdx.x];
    xb[threadIdx.x] = (v - mu[s]) * rs[s] * gg[s] + bb[s];
  }
  __syncthreads();
  int d = threadIdx.x;
  float a0 = 0.f, a1 = 0.f;
  for (int j = 0; j < NNODE; ++j) {
    float xv = xb[j];
    a0 += xv * W[(size_t)j*DD + d];
    a1 += xv * W[(size_t)j*DD + d + 256];
  }
  size_t o = (size_t)tok*DD + d;
  u16 h, l;
  f2bsplit(a0, h, l); Th[o] = h; Tl[o] = l;
  f2bsplit(a1, h, l); Th[o+256] = h; Tl[o+256] = l;
}

// ---------------- fp32 GEMM (only for Wcomb = W_emb1 @ conv1_W) ----------------
__global__ __launch_bounds__(256) void gemm_kernel(const float* __restrict__ A,
    const float* __restrict__ B, float* __restrict__ C, int M, int N, int K) {
  __shared__ float As[16][68];
  __shared__ float Bs[16][68];
  int bm = blockIdx.y * 64, bn = blockIdx.x * 64;
  int tid = threadIdx.x;
  int tx = tid & 15, ty = tid >> 4;
  float acc[4][4] = {};
  for (int k0 = 0; k0 < K; k0 += 16) {
    {
      int row = tid >> 2; int kk = (tid & 3) * 4;
      int gm = bm + row;
      #pragma unroll
      for (int i = 0; i < 4; ++i) {
        int gk = k0 + kk + i;
        As[kk+i][row] = (gm < M && gk < K) ? A[(size_t)gm*K + gk] : 0.f;
      }
    }
    {
      int krow = tid >> 4; int nn = (tid & 15) * 4;
      int gk = k0 + krow;
      #pragma unroll
      for (int i = 0; i < 4; ++i) {
        int gn = bn + nn + i;
        Bs[krow][nn+i] = (gk < K && gn < N) ? B[(size_t)gk*N + gn] : 0.f;
      }
    }
    __syncthreads();
    #pragma unroll
    for (int k = 0; k < 16; ++k) {
      float a[4], bb2[4];
      #pragma unroll
      for (int i = 0; i < 4; ++i) a[i] = As[k][ty*4+i];
      #pragma unroll
      for (int j = 0; j < 4; ++j) bb2[j] = Bs[k][tx*4+j];
      #pragma unroll
      for (int i = 0; i < 4; ++i)
        #pragma unroll
        for (int j = 0; j < 4; ++j) acc[i][j] += a[i]*bb2[j];
    }
    __syncthreads();
  }
  #pragma unroll
  for (int i = 0; i < 4; ++i) {
    int gm = bm + ty*4 + i;
    if (gm >= M) continue;
    #pragma unroll
    for (int j = 0; j < 4; ++j) {
      int gn = bn + tx*4 + j;
      if (gn >= N) continue;
      C[(size_t)gm*N + gn] = acc[i][j];
    }
  }
}

// ---------------- transpose+split tile helper ----------------
__device__ __forceinline__ void transpose_split_tile(const float* __restrict__ W,
    u16* __restrict__ th, u16* __restrict__ tl,
    int K, int N, int Kp, int bx, int by, float (*t)[65]) {
  int k0 = by*64, n0 = bx*64;
  for (int i = threadIdx.x; i < 64*64; i += 256) {
    int r = i >> 6, c = i & 63;
    int gk = k0 + r, gn = n0 + c;
    t[r][c] = (gk < K && gn < N) ? W[(size_t)gk*N + gn] : 0.f;
  }
  __syncthreads();
  for (int i = threadIdx.x; i < 64*64; i += 256) {
    int r = i >> 6, c = i & 63;
    int gn = n0 + r, gk = k0 + c;
    u16 h, l; f2bsplit(t[c][r], h, l);
    th[(size_t)gn*Kp + gk] = h;
    tl[(size_t)gn*Kp + gk] = l;
  }
}

// ---------------- ALL layers batched weight transpose ----------------
__global__ __launch_bounds__(256) void allT_kernel(
    const float* __restrict__ Wqkv, const float* __restrict__ Wo,
    const float* __restrict__ W1, const float* __restrict__ W2,
    u16* WQh, u16* WQl, u16* WOh, u16* WOl,
    u16* W1h, u16* W1l, u16* W2h, u16* W2l) {
  __shared__ float t[64][65];
  int layer = blockIdx.x / 768;
  int b = blockIdx.x % 768;
  const float* wqkv = Wqkv + (size_t)layer*DD*3*DD;
  const float* wo   = Wo   + (size_t)layer*DD*DD;
  const float* w1   = W1   + (size_t)layer*DD*DFF;
  const float* w2   = W2   + (size_t)layer*DFF*DD;
  size_t oq = (size_t)layer*1536*512, oo = (size_t)layer*512*512;
  size_t o1 = (size_t)layer*2048*512, o2 = (size_t)layer*512*2048;
  if (b < 192)      transpose_split_tile(wqkv, WQh+oq, WQl+oq, 512, 1536, 512, b % 24, b / 24, t);
  else if (b < 256) { int q = b - 192; transpose_split_tile(wo, WOh+oo, WOl+oo, 512, 512, 512, q % 8, q / 8, t); }
  else if (b < 512) { int q = b - 256; transpose_split_tile(w1, W1h+o1, W1l+o1, 512, 2048, 512, q % 32, q / 32, t); }
  else              { int q = b - 512; transpose_split_tile(w2, W2h+o2, W2l+o2, 2048, 512, 2048, q % 8, q / 8, t); }
}

// ---------------- GCN weights transpose (Wcomb, convs_W[0..2]) ----------------
__global__ __launch_bounds__(256) void gcnT_kernel(
    const float* __restrict__ WC, const float* __restrict__ convs_W,
    u16* CTh, u16* CTl, u16* CVh, u16* CVl) {
  __shared__ float t[64][65];
  int job = blockIdx.x >> 6, q = blockIdx.x & 63;
  int bx = q % 8, by = q / 8;
  if (job == 0) transpose_split_tile(WC, CTh, CTl, 512, 512, 512, bx, by, t);
  else {
    int l = job - 1;
    transpose_split_tile(convs_W + (size_t)l*DD*DD,
        CVh + (size_t)l*DD*DD, CVl + (size_t)l*DD*DD, 512, 512, 512, bx, by, t);
  }
}

// ---------------- split-bf16 MFMA GEMM: 128x256 tile, 4 waves of 64x128 ----------------
// Counted-vmcnt 2-phase dbuf; LDS 96KB (1 block/CU). j-outer B-frag consumption keeps VGPR low.
// OUTMODE: 0 fp32 [M][Nstride]; 1 split-bf16 linear; 2 fp32 attn tiles.
template<bool RELU, int OUTMODE>
__global__ __launch_bounds__(256, 1) void gemm3_kernel(
    const u16* __restrict__ Ah, const u16* __restrict__ Al,
    const u16* __restrict__ Bh, const u16* __restrict__ Bl,
    const float* __restrict__ bias,
    float* __restrict__ Cf, u16* __restrict__ Ch, u16* __restrict__ Cl,
    int Nreal, int Nstride, int Kp, int KC) {
  __shared__ alignas(16) u16 sA[2][2][4096];    // [buf][hi/lo][128*32]
  __shared__ alignas(16) u16 sB[2][2][8192];    // [buf][hi/lo][256*32]
  unsigned nx = gridDim.x, ny = gridDim.y;
  unsigned nwg = nx * ny * gridDim.z;
  unsigned lb = blockIdx.x + nx*(blockIdx.y + ny*blockIdx.z);
  // bijective XCD swizzle (m204): works for any nwg
  unsigned qd = nwg >> 3, rm = nwg & 7u;
  unsigned xcd = lb & 7u, idx = lb >> 3;
  unsigned basep = (xcd < rm) ? xcd*(qd+1) : rm*(qd+1) + (xcd-rm)*qd;
  unsigned swz = basep + idx;
  unsigned bxi = swz % nx;
  unsigned rem = swz / nx;
  unsigned byi = rem % ny;
  unsigned bzi = rem / ny;
  int bm = byi * 128, bn = bxi * 256;
  int z = bzi;
  int tid = threadIdx.x;
  int wv = tid >> 6, lane = tid & 63;
  int wr = (wv >> 1) * 64, wc = (wv & 1) * 128;
  f32x4 acc[4][8];
  #pragma unroll
  for (int i = 0; i < 4; ++i)
    #pragma unroll
    for (int j = 0; j < 8; ++j) acc[i][j] = (f32x4){0.f,0.f,0.f,0.f};

  int r0 = tid >> 2;                 // rows 0..63 per 256-thread sweep
  int lin = (tid & 3) * 8;
  int fr = lane & 15, fo = (lane >> 4) * 8;

  int kbeg = z * KC;
  // staging pointers (hi); lo via uniform deltas
  int cA0 = lin ^ (((r0 >> 1) & 3) << 3);
  int cA1 = lin ^ ((((r0+64) >> 1) & 3) << 3);
  const u16* pA0 = Ah + (size_t)(bm + r0)*Kp + kbeg + cA0;
  const u16* pA1 = Ah + (size_t)(bm + r0 + 64)*Kp + kbeg + cA1;
  const u16* pB0 = Bh + (size_t)(bn + r0)*Kp + kbeg + cA0;
  const u16* pB1 = Bh + (size_t)(bn + r0 + 64)*Kp + kbeg + cA1;
  const u16* pB2 = Bh + (size_t)(bn + r0 + 128)*Kp + kbeg + cA0;
  const u16* pB3 = Bh + (size_t)(bn + r0 + 192)*Kp + kbeg + cA1;
  const ptrdiff_t dA = Al - Ah;
  const ptrdiff_t dB = Bl - Bh;

  auto stage = [&](int bi) {
    load_lds16(pA0,      &sA[bi][0][tid*8]);
    load_lds16(pA1,      &sA[bi][0][2048 + tid*8]);
    load_lds16(pA0 + dA, &sA[bi][1][tid*8]);
    load_lds16(pA1 + dA, &sA[bi][1][2048 + tid*8]);
    load_lds16(pB0,      &sB[bi][0][tid*8]);
    load_lds16(pB1,      &sB[bi][0][2048 + tid*8]);
    load_lds16(pB2,      &sB[bi][0][4096 + tid*8]);
    load_lds16(pB3,      &sB[bi][0][6144 + tid*8]);
    load_lds16(pB0 + dB, &sB[bi][1][tid*8]);
    load_lds16(pB1 + dB, &sB[bi][1][2048 + tid*8]);
    load_lds16(pB2 + dB, &sB[bi][1][4096 + tid*8]);
    load_lds16(pB3 + dB, &sB[bi][1][6144 + tid*8]);
    pA0 += 32; pA1 += 32; pB0 += 32; pB1 += 32; pB2 += 32; pB3 += 32;
  };

  int nk = KC >> 5;
  stage(0);
  int cur = 0;
  for (int t = 0; t < nk; ++t) {
    if (t + 1 < nk) {
      stage(cur ^ 1);
      asm volatile("s_waitcnt vmcnt(12)" ::: "memory");   // cur landed; next in flight
    } else {
      asm volatile("s_waitcnt vmcnt(0)" ::: "memory");
    }
    __builtin_amdgcn_s_barrier();
    __builtin_amdgcn_sched_barrier(0);
    bf16x8 ah[4], al[4];
    #pragma unroll
    for (int i = 0; i < 4; ++i) {
      int ra = wr + i*16 + fr;
      int ea = ra*32 + (fo ^ (((ra >> 1) & 3) << 3));
      ah[i] = *(const bf16x8*)&sA[cur][0][ea];
      al[i] = *(const bf16x8*)&sA[cur][1][ea];
    }
    #pragma unroll
    for (int j = 0; j < 8; ++j) {
      int rb = wc + j*16 + fr;
      int eb = rb*32 + (fo ^ (((rb >> 1) & 3) << 3));
      bf16x8 bh = *(const bf16x8*)&sB[cur][0][eb];
      bf16x8 bl = *(const bf16x8*)&sB[cur][1][eb];
      #pragma unroll
      for (int i = 0; i < 4; ++i) {
        acc[i][j] = __builtin_amdgcn_mfma_f32_16x16x32_bf16(ah[i], bh, acc[i][j], 0, 0, 0);
        acc[i][j] = __builtin_amdgcn_mfma_f32_16x16x32_bf16(ah[i], bl, acc[i][j], 0, 0, 0);
        acc[i][j] = __builtin_amdgcn_mfma_f32_16x16x32_bf16(al[i], bh, acc[i][j], 0, 0, 0);
      }
    }
    __builtin_amdgcn_s_barrier();
    cur ^= 1;
  }
  size_t pstride = (size_t)gridDim.y * 128 * Nstride;
  int cr = (lane >> 4) * 4, cc = lane & 15;
  #pragma unroll
  for (int i = 0; i < 4; ++i) {
    #pragma unroll
    for (int j = 0; j < 8; ++j) {
      int gn = bn + wc + j*16 + cc;
      if (gn >= Nstride) continue;
      #pragma unroll
      for (int q = 0; q < 4; ++q) {
        int gm = bm + wr + i*16 + cr + q;
        float v = acc[i][j][q];
        if (gn < Nreal) { if (bias && z == 0) v += bias[gn]; } else v = 0.f;
        if (RELU) v = fmaxf(v, 0.f);
        if (OUTMODE == 0) {
          Cf[(size_t)z*pstride + (size_t)gm*Nstride + gn] = v;
        } else if (OUTMODE == 1) {
          size_t o = (size_t)z*pstride + (size_t)gm*Nstride + gn;
          u16 h, l; f2bsplit(v, h, l);
          Ch[o] = h; Cl[o] = l;
        } else {
          int which = gn >> 9, hh2 = (gn >> 6) & 7, d = gn & 63;
          int b2 = gm & 127, s2 = gm >> 7;
          Cf[(size_t)((which*NH + hh2)*MG + b2)*4096 + s2*64 + d] = v;
        }
      }
    }
  }
}

// ---------------- MFMA attention per (b,h): fp32 in, in-register split-bf16 ----------------
__global__ __launch_bounds__(256) void attn_kernel(const float* __restrict__ QKV,
    u16* __restrict__ Oh, u16* __restrict__ Ol) {
  int b = blockIdx.x >> 3, h = blockIdx.x & 7;
  __shared__ float sQ[64*PW];
  __shared__ float sK[64*PW];
  __shared__ float sV[64*PW];
  u16* sPh = (u16*)sK;
  u16* sPl = ((u16*)sK) + 4096;
  float* Ss = sQ;
  int tid = threadIdx.x, wv = tid >> 6, lane = tid & 63;
  int fr = lane & 15, fq = lane >> 4;
  size_t base0 = (size_t)(h*MG + b)*4096;
  const float* Qg = QKV + base0;
  const float* Kg = QKV + (size_t)NH*MG*4096 + base0;
  const float* Vg = QKV + (size_t)2*NH*MG*4096 + base0;
  #pragma unroll
  for (int i = 0; i < 4; ++i) {
    int c = tid + i*256;
    int r = c >> 4, col = (c & 15) * 4;
    f32x4 q4 = *(const f32x4*)(Qg + (size_t)c*4);
    f32x4 k4 = *(const f32x4*)(Kg + (size_t)c*4);
    f32x4 v4 = *(const f32x4*)(Vg + (size_t)c*4);
    *(f32x4*)&sQ[r*PW + col] = q4;
    *(f32x4*)&sK[r*PW + col] = k4;
    *(f32x4*)&sV[r*PW + col] = v4;
  }
  if (tid < 128) sV[(62 + (tid >> 6))*PW + (tid & 63)] = 0.f;
  __syncthreads();
  int rA = 16*wv + fr;
  bf16x8 qh[2], ql[2];
  #pragma unroll
  for (int kk = 0; kk < 2; ++kk)
    cvt8(&sQ[rA*PW + 32*kk + 8*fq], qh[kk], ql[kk]);
  __syncthreads();
  // ---- QK^T ----
  f32x4 accS[4];
  #pragma unroll
  for (int j = 0; j < 4; ++j) accS[j] = (f32x4){0.f,0.f,0.f,0.f};
  __builtin_amdgcn_s_setprio(1);
  #pragma unroll
  for (int kk = 0; kk < 2; ++kk) {
    #pragma unroll
    for (int j = 0; j < 4; ++j) {
      int rB = 16*j + fr;
      bf16x8 kh, kl;
      cvt8(&sK[rB*PW + 32*kk + 8*fq], kh, kl);
      accS[j] = __builtin_amdgcn_mfma_f32_16x16x32_bf16(qh[kk], kh, accS[j], 0, 0, 0);
      accS[j] = __builtin_amdgcn_mfma_f32_16x16x32_bf16(qh[kk], kl, accS[j], 0, 0, 0);
      accS[j] = __builtin_amdgcn_mfma_f32_16x16x32_bf16(ql[kk], kh, accS[j], 0, 0, 0);
    }
  }
  __builtin_amdgcn_s_setprio(0);
  #pragma unroll
  for (int j = 0; j < 4; ++j)
    #pragma unroll
    for (int q = 0; q < 4; ++q)
      Ss[(16*wv + fq*4 + q)*PW + 16*j + fr] = accS[j][q];
  __syncthreads();
  // ---- softmax ----
  for (int rr = 0; rr < 16; ++rr) {
    int row = 16*wv + rr;
    float sv = (lane < NNODE) ? Ss[row*PW + lane]*0.125f : -FLT_MAX;
    float mx = wave_max(sv);
    float e = (lane < NNODE) ? expf(sv - mx) : 0.f;
    float sm = wave_sum(e);
    float p = e / sm;
    u16 ph, pl; f2bsplit(p, ph, pl);
    int pos = row*64 + ((((lane >> 3) ^ (row & 7)) << 3) | (lane & 7));
    sPh[pos] = ph; sPl[pos] = pl;
  }
  __syncthreads();
  // ---- PV ----
  f32x4 accO[4];
  #pragma unroll
  for (int j = 0; j < 4; ++j) accO[j] = (f32x4){0.f,0.f,0.f,0.f};
  __builtin_amdgcn_s_setprio(1);
  #pragma unroll
  for (int kk = 0; kk < 2; ++kk) {
    int cha = (((4*kk + fq) ^ (rA & 7)) << 3);
    bf16x8 pah = *(const bf16x8*)&sPh[rA*64 + cha];
    bf16x8 pal = *(const bf16x8*)&sPl[rA*64 + cha];
    #pragma unroll
    for (int j = 0; j < 4; ++j) {
      bf16x8 vh, vl;
      cvt8s(&sV[(32*kk + 8*fq)*PW + 16*j + fr], vh, vl);
      accO[j] = __builtin_amdgcn_mfma_f32_16x16x32_bf16(pah, vh, accO[j], 0, 0, 0);
      accO[j] = __builtin_amdgcn_mfma_f32_16x16x32_bf16(pah, vl, accO[j], 0, 0, 0);
      accO[j] = __builtin_amdgcn_mfma_f32_16x16x32_bf16(pal, vh, accO[j], 0, 0, 0);
    }
  }
  __builtin_amdgcn_s_setprio(0);
  #pragma unroll
  for (int j = 0; j < 4; ++j) {
    #pragma unroll
    for (int q = 0; q < 4; ++q) {
      int s2 = 16*wv + fq*4 + q;
      if (s2 < NNODE) {
        int d = 16*j + fr;
        size_t o = ((size_t)(s2*MG + b))*DD + h*DH + d;
        u16 hh2, ll2; f2bsplit(accO[j][q], hh2, ll2);
        Oh[o] = hh2; Ol[o] = ll2;
      }
    }
  }
}

// ---------------- LayerNorm(residual(split) + sum_z PART[z]) -> split ----------------
__global__ __launch_bounds__(256) void add_ln_kernel(
    u16* __restrict__ Xh, u16* __restrict__ Xl,
    const float* __restrict__ P, int nchunk,
    const float* __restrict__ gg, const float* __restrict__ bb) {
  size_t row = blockIdx.x;
  int t = threadIdx.x;
  const size_t MN = (size_t)NTOK*DD;
  float r0 = 0.f, r1 = 0.f;
  for (int z = 0; z < nchunk; ++z) {
    r0 += P[z*MN + row*DD + t];
    r1 += P[z*MN + row*DD + t + 256];
  }
  float v0 = b2f(Xh[row*DD + t]) + b2f(Xl[row*DD + t]) + r0;
  float v1 = b2f(Xh[row*DD + t + 256]) + b2f(Xl[row*DD + t + 256]) + r1;
  __shared__ float red[4];
  float s = wave_sum(v0 + v1);
  int wv = t >> 6, lane = t & 63;
  if (lane == 0) red[wv] = s;
  __syncthreads();
  float mu = (red[0]+red[1]+red[2]+red[3]) * (1.f/DD);
  float d0 = v0 - mu, d1 = v1 - mu;
  float q = wave_sum(d0*d0 + d1*d1);
  __syncthreads();
  if (lane == 0) red[wv] = q;
  __syncthreads();
  float var = (red[0]+red[1]+red[2]+red[3]) * (1.f/DD);
  float rs = rsqrtf(var + EPSV);
  float o0 = d0*rs*gg[t] + bb[t];
  float o1 = d1*rs*gg[t+256] + bb[t+256];
  u16 h, l;
  f2bsplit(o0, h, l); Xh[row*DD + t] = h; Xl[row*DD + t] = l;
  f2bsplit(o1, h, l); Xh[row*DD + t+256] = h; Xl[row*DD + t+256] = l;
}

// ---------------- graph-structure helpers ----------------
__global__ void fill_int_kernel(int* p, int v, int n) {
  int i = blockIdx.x*256 + threadIdx.x;
  if (i < n) p[i] = v;
}
__global__ void zero_f_kernel(float* p, int n) {
  int i = blockIdx.x*256 + threadIdx.x;
  if (i < n) p[i] = 0.f;
}
__global__ void count_deg_kernel(const int* __restrict__ dst, int* deg, int n) {
  int e = blockIdx.x*256 + threadIdx.x;
  if (e < n) atomicAdd(&deg[dst[e]], 1);
}
__global__ void dis_kernel(const int* __restrict__ deg, float* dis, int n) {
  int i = blockIdx.x*256+threadIdx.x;
  if (i < n) dis[i] = rsqrtf((float)deg[i]);
}
__global__ void coef0_kernel(const int* __restrict__ src, const int* __restrict__ dst,
                             const float* __restrict__ dis, float* coef) {
  int e = blockIdx.x*256+threadIdx.x;
  if (e < NEDGE) coef[e] = dis[src[e]]*dis[dst[e]];
}
__global__ void coef1_kernel(const int* __restrict__ src, const int* __restrict__ dst,
                             const int* __restrict__ keep,
                             const float* __restrict__ dis, float* coef) {
  int e = blockIdx.x*256+threadIdx.x;
  if (e < NEDGE) coef[e] = keep[e] ? dis[src[e]]*dis[dst[e]] : 0.f;
}

// ---------------- dense per-graph normalized adjacency build ----------------
__global__ __launch_bounds__(64) void diagA_kernel(const float* __restrict__ dis,
    float* __restrict__ AG, int NP) {
  int g = blockIdx.x, lane = threadIdx.x;
  if (lane < NP) {
    float d = dis[g*NP + lane];
    AG[(size_t)g*4096 + lane*64 + lane] = d*d;
  }
}
__global__ __launch_bounds__(256) void edgeA_kernel(const int* __restrict__ src,
    const int* __restrict__ dst, const float* __restrict__ coef,
    float* __restrict__ AG, int NP) {
  int e = blockIdx.x*256 + threadIdx.x;
  if (e >= NEDGE) return;
  float c = coef[e];
  if (c == 0.f) return;
  int g = e / EPG;
  int ls = src[e] - g*NP, ld = dst[e] - g*NP;
  atomicAdd(&AG[(size_t)g*4096 + ld*64 + ls], c);
}

// ---------------- dense GCN aggregation ----------------
__global__ __launch_bounds__(256) void dense_agg_kernel(
    const float* __restrict__ AG,
    const float* __restrict__ P, int nchunk, size_t mn,
    const float* __restrict__ bias,
    float* __restrict__ Hout, int NP, int relu,
    u16* __restrict__ outh, u16* __restrict__ outl) {
  int g = blockIdx.x >> 3;
  int ct = (blockIdx.x & 7) * 64;
  __shared__ float hls[64*64];
  __shared__ float At[64*68];
  int base = g * NP;
  for (int idx = threadIdx.x; idx < 64*64; idx += 256) {
    int r = idx >> 6, c = idx & 63;
    float v = 0.f;
    if (r < NP) {
      for (int z = 0; z < nchunk; ++z)
        v += P[z*mn + (size_t)(base+r)*DD + ct + c];
    }
    hls[idx] = v;
    At[c*68 + r] = AG[(size_t)g*4096 + idx];
  }
  __syncthreads();
  int wv = threadIdx.x >> 6, lane = threadIdx.x & 63;
  int i0 = wv * 16;
  f32x4 acc[4];
  #pragma unroll
  for (int q = 0; q < 4; ++q) acc[q] = (f32x4){0.f,0.f,0.f,0.f};
  for (int j = 0; j < NP; ++j) {
    float hv = hls[j*64 + lane];
    const f32x4* ap = (const f32x4*)&At[j*68 + i0];
    f32x4 a0 = ap[0], a1 = ap[1], a2 = ap[2], a3 = ap[3];
    #pragma unroll
    for (int t = 0; t < 4; ++t) {
      acc[0][t] += a0[t] * hv;
      acc[1][t] += a1[t] * hv;
      acc[2][t] += a2[t] * hv;
      acc[3][t] += a3[t] * hv;
    }
  }
  float bv = bias[ct + lane];
  #pragma unroll
  for (int q = 0; q < 4; ++q) {
    #pragma unroll
    for (int t = 0; t < 4; ++t) {
      int i = i0 + q*4 + t;
      if (i < NP) {
        float v = acc[q][t] + bv;
        if (relu) v = fmaxf(v, 0.f);
        size_t o = (size_t)(base+i)*DD + ct + lane;
        Hout[o] = v;
        if (outh) { u16 h, l; f2bsplit(v, h, l); outh[o] = h; outl[o] = l; }
      }
    }
  }
}

// ---------------- dense SAGPool score ----------------
__global__ __launch_bounds__(64) void dense_score_kernel(
    const float* __restrict__ AG, const float* __restrict__ hsv,
    const float* __restrict__ pb, float* __restrict__ sc, int NP) {
  int g = blockIdx.x, lane = threadIdx.x;
  __shared__ float hls[64];
  __shared__ float At[64*65];
  hls[lane] = (lane < NP) ? hsv[g*NP + lane] : 0.f;
  for (int idx = lane; idx < 64*64; idx += 64) {
    int i = idx >> 6, j = idx & 63;
    At[j*65 + i] = AG[(size_t)g*4096 + idx];
  }
  __syncthreads();
  if (lane < NP) {
    float acc = 0.f;
    for (int j = 0; j < NP; ++j) acc += At[j*65 + lane] * hls[j];
    sc[g*NP + lane] = acc + pb[0];
  }
}

// ---------------- gemv ----------------
__global__ __launch_bounds__(256) void gemv_kernel(const float* __restrict__ h,
    const float* __restrict__ wv, float* __restrict__ out, int n) {
  int node = blockIdx.x*4 + (threadIdx.x >> 6);
  int lane = threadIdx.x & 63;
  if (node >= n) return;
  const float* row = h + (size_t)node*DD;
  float acc = 0.f;
  for (int d = lane; d < DD; d += 64) acc += row[d]*wv[d];
  acc = wave_sum(acc);
  if (lane == 0) out[node] = acc;
}

// ---------------- per-graph top-k ----------------
__global__ __launch_bounds__(64) void topk_kernel(const float* __restrict__ sc,
    int* __restrict__ perm, int NP, int KK) {
  int g = blockIdx.x, lane = threadIdx.x;
  float v = (lane < NP) ? sc[g*NP+lane] : -FLT_MAX;
  for (int r = 0; r < KK; ++r) {
    float bv = v; int bi = lane;
    for (int off = 32; off; off >>= 1) {
      float ov = __shfl_xor(bv, off);
      int oi = __shfl_xor(bi, off);
      if (ov > bv || (ov == bv && oi < bi)) { bv = ov; bi = oi; }
    }
    if (lane == 0) perm[g*KK + r] = bi;
    if (lane == bi) v = -FLT_MAX;
  }
}

// ---------------- gather pooled ----------------
__global__ __launch_bounds__(256) void gather_kernel(const float* __restrict__ h,
    const float* __restrict__ sc, const int* __restrict__ perm,
    float* __restrict__ xn, u16* __restrict__ outh, u16* __restrict__ outl,
    int NP, int KK) {
  int j = blockIdx.x;
  int g = j / KK;
  int pi = perm[j];
  float t = tanhf(sc[g*NP + pi]);
  const float* srow = h + (size_t)(g*NP + pi)*DD;
  size_t o = (size_t)j*DD + threadIdx.x;
  float v0 = srow[threadIdx.x]*t;
  float v1 = srow[threadIdx.x+256]*t;
  xn[o] = v0; xn[o+256] = v1;
  if (outh) {
    u16 hh, ll;
    f2bsplit(v0, hh, ll); outh[o] = hh; outl[o] = ll;
    f2bsplit(v1, hh, ll); outh[o+256] = hh; outl[o+256] = ll;
  }
}

__global__ void nmap_scatter_kernel(const int* __restrict__ perm, int* __restrict__ nmap) {
  int j = blockIdx.x*256 + threadIdx.x;
  if (j < MG*KP1) nmap[(j/KP1)*NNODE + perm[j]] = j;
}

__global__ void filter_kernel(const int* __restrict__ src0, const int* __restrict__ dst0,
    const int* __restrict__ nmap, int* __restrict__ es, int* __restrict__ ed,
    int* __restrict__ keep, int* __restrict__ deg1) {
  int e = blockIdx.x*256+threadIdx.x;
  if (e >= NEDGE) return;
  int ns = nmap[src0[e]], nd = nmap[dst0[e]];
  int k = (ns >= 0) && (nd >= 0);
  es[e] = k ? ns : 0;
  ed[e] = k ? nd : 0;
  keep[e] = k;
  if (k) atomicAdd(&deg1[nd], 1);
}

// ---------------- readout: gmp || gap ----------------
__global__ __launch_bounds__(256) void readout_kernel(const float* __restrict__ h,
    float* __restrict__ z, int KK, int acc) {
  int g = blockIdx.x;
  for (int c = threadIdx.x; c < DD; c += 256) {
    float mx = -FLT_MAX, sm = 0.f;
    for (int r = 0; r < KK; ++r) {
      float v = h[(size_t)(g*KK+r)*DD + c];
      mx = fmaxf(mx, v); sm += v;
    }
    float mean = sm / (float)KK;
    if (acc) { z[(size_t)g*1024 + c] += mx; z[(size_t)g*1024 + 512 + c] += mean; }
    else     { z[(size_t)g*1024 + c]  = mx; z[(size_t)g*1024 + 512 + c]  = mean; }
  }
}

// ---------------- MLP head stage 1 ----------------
__global__ __launch_bounds__(256) void mlp1_kernel(const float* __restrict__ Z,
    const float* __restrict__ W1, float* __restrict__ Pm) {
  int b = blockIdx.x;
  int g = b >> 2, zc = b & 3;
  __shared__ float z[256];
  int t = threadIdx.x;
  z[t] = Z[(size_t)g*1024 + zc*256 + t];
  __syncthreads();
  const float* Wb = W1 + (size_t)zc*256*512;
  float a0 = 0.f, a1 = 0.f;
  for (int k = 0; k < 256; ++k) {
    float zv = z[k];
    a0 += zv * Wb[(size_t)k*512 + t];
    a1 += zv * Wb[(size_t)k*512 + t + 256];
  }
  size_t o = ((size_t)zc*MG + g)*512;
  Pm[o + t] = a0;
  Pm[o + t + 256] = a1;
}

// ---------------- MLP head stage 2 ----------------
__global__ __launch_bounds__(256) void mlp2_kernel(const float* __restrict__ Pm,
    const float* __restrict__ b1,
    const float* __restrict__ W2, const float* __restrict__ b2,
    const float* __restrict__ W3, const float* __restrict__ b3,
    float* __restrict__ out) {
  int g = blockIdx.x;
  int t = threadIdx.x;
  int wv = t >> 6, lane = t & 63;
  __shared__ float h1[512];
  __shared__ float p2[4][256];
  __shared__ float h2[256];
  #pragma unroll
  for (int half = 0; half < 2; ++half) {
    int n = t + half*256;
    float a = b1[n];
    #pragma unroll
    for (int zc = 0; zc < 4; ++zc) a += Pm[((size_t)zc*MG + g)*512 + n];
    h1[n] = fmaxf(a, 0.f);
  }
  __syncthreads();
  {
    float a[4] = {0.f, 0.f, 0.f, 0.f};
    for (int k = wv*128; k < wv*128 + 128; ++k) {
      float hv = h1[k];
      #pragma unroll
      for (int q = 0; q < 4; ++q)
        a[q] += hv * W2[(size_t)k*256 + lane + q*64];
    }
    #pragma unroll
    for (int q = 0; q < 4; ++q) p2[wv][lane + q*64] = a[q];
  }
  __syncthreads();
  h2[t] = fmaxf(p2[0][t] + p2[1][t] + p2[2][t] + p2[3][t] + b2[t], 0.f);
  __syncthreads();
  if (wv < 2) {
    float acc = 0.f;
    for (int k = lane; k < 256; k += 64) acc += h2[k]*W3[(size_t)k*2 + wv];
    acc = wave_sum(acc);
    if (lane == 0) out[(size_t)g*2 + wv] = acc + b3[wv];
  }
}

extern "C" void kernel_launch(void* const* d_in, const int* in_sizes, int n_in,
                              void* d_out, int out_size, void* d_ws, size_t ws_size,
                              hipStream_t stream) {
  const float* x       = (const float*)d_in[0];
  const int*   edge    = (const int*)d_in[1];
  const float* bn_g    = (const float*)d_in[2];
  const float* bn_b    = (const float*)d_in[3];
  const float* W_emb   = (const float*)d_in[4];
  const float* Wqkv    = (const float*)d_in[5];
  const float* bqkv    = (const float*)d_in[6];
  const float* Wo      = (const float*)d_in[7];
  const float* bo      = (const float*)d_in[8];
  const float* W1      = (const float*)d_in[9];
  const float* b1      = (const float*)d_in[10];
  const float* W2      = (const float*)d_in[11];
  const float* b2      = (const float*)d_in[12];
  const float* g1      = (const float*)d_in[13];
  const float* be1     = (const float*)d_in[14];
  const float* g2      = (const float*)d_in[15];
  const float* be2     = (const float*)d_in[16];
  const float* W_emb1  = (const float*)d_in[17];
  const float* conv1_W = (const float*)d_in[18];
  const float* conv1_b = (const float*)d_in[19];
  const float* convs_W = (const float*)d_in[20];
  const float* convs_b = (const float*)d_in[21];
  const float* pool1_W = (const float*)d_in[22];
  const float* pool1_b = (const float*)d_in[23];
  const float* pool2_W = (const float*)d_in[24];
  const float* pool2_b = (const float*)d_in[25];
  const float* fc1_W   = (const float*)d_in[26];
  const float* fc1_b   = (const float*)d_in[27];
  const float* fc2_W   = (const float*)d_in[28];
  const float* fc2_b   = (const float*)d_in[29];
  const float* fc3_W   = (const float*)d_in[30];
  const float* fc3_b   = (const float*)d_in[31];
  (void)in_sizes; (void)n_in; (void)out_size; (void)ws_size;

  const int* srcp = edge;
  const int* dstp = edge + NEDGE;

  char* wsb = (char*)d_ws;
  size_t off = 0;
  auto alloc = [&](size_t bytes)->void* {
    void* p = wsb + off;
    off += (bytes + 255) & ~(size_t)255;
    return p;
  };
  const size_t MN = (size_t)NTOK*DD;
  size_t qkvB = (size_t)3*NH*MG*4096*4, ffnB = (size_t)NTOK*DFF*2*2;
  char* BIGU  = (char*)alloc(qkvB > ffnB ? qkvB : ffnB);
  u16* BIGh   = (u16*)BIGU;
  u16* BIGl   = BIGh + (size_t)NTOK*DFF;
  float* QKVf = (float*)BIGU;
  float* PART = (float*)alloc(4*MN*4);
  u16* Th   = (u16*)alloc(MN*2);
  u16* Tl   = (u16*)alloc(MN*2);
  u16* ATh  = (u16*)alloc(MN*2);
  u16* ATl  = (u16*)alloc(MN*2);
  u16* Hh   = (u16*)alloc((size_t)MG*KP1*DD*2);
  u16* Hl   = (u16*)alloc((size_t)MG*KP1*DD*2);
  u16* WQh  = (u16*)alloc((size_t)4*1536*512*2);
  u16* WQl  = (u16*)alloc((size_t)4*1536*512*2);
  u16* WOh  = (u16*)alloc((size_t)4*512*512*2);
  u16* WOl  = (u16*)alloc((size_t)4*512*512*2);
  u16* W1h  = (u16*)alloc((size_t)4*2048*512*2);
  u16* W1l  = (u16*)alloc((size_t)4*2048*512*2);
  u16* W2h  = (u16*)alloc((size_t)4*512*2048*2);
  u16* W2l  = (u16*)alloc((size_t)4*512*2048*2);
  float* WCf = (float*)alloc((size_t)512*512*4);
  u16* CTh  = (u16*)alloc((size_t)512*512*2);
  u16* CTl  = (u16*)alloc((size_t)512*512*2);
  u16* CVh  = (u16*)alloc((size_t)3*512*512*2);
  u16* CVl  = (u16*)alloc((size_t)3*512*512*2);
  float* AG0 = (float*)alloc((size_t)MG*4096*4);
  float* AG1 = (float*)alloc((size_t)MG*4096*4);
  float* MU   = (float*)alloc(NNODE*4);
  float* RS   = (float*)alloc(NNODE*4);
  int*   DEG0 = (int*)alloc(NTOK*4);
  float* DIS0 = (float*)alloc(NTOK*4);
  float* COEF0= (float*)alloc(NEDGE*4);
  float* HS   = (float*)alloc(NTOK*4);
  float* SC   = (float*)alloc(NTOK*4);
  int*   PERM1= (int*)alloc(MG*KP1*4);
  int*   NMAP = (int*)alloc(NTOK*4);
  int*   ES1  = (int*)alloc(NEDGE*4);
  int*   ED1  = (int*)alloc(NEDGE*4);
  int*   KEEP1= (int*)alloc(NEDGE*4);
  int*   DEG1 = (int*)alloc(MG*KP1*4);
  float* DIS1 = (float*)alloc(MG*KP1*4);
  float* COEF1= (float*)alloc(NEDGE*4);
  int*   PERM2= (int*)alloc(MG*KP2*4);
  float* Z    = (float*)alloc(MG*1024*4);
  float* Pm   = (float*)alloc((size_t)4*MG*512*4);

  float* PA = PART;
  float* PB = PART + 2*MN;

  // ---- prep ----
  bn_stats_kernel<<<NNODE, 256, 0, stream>>>(x, MU, RS);
  embed_kernel<<<NTOK, 256, 0, stream>>>(x, MU, RS, bn_g, bn_b, W_emb, Th, Tl);
  allT_kernel<<<4*768, 256, 0, stream>>>(Wqkv, Wo, W1, W2,
      WQh, WQl, WOh, WOl, W1h, W1l, W2h, W2l);
  fill_int_kernel<<<(NTOK+255)/256, 256, 0, stream>>>(DEG0, 1, NTOK);
  count_deg_kernel<<<(NEDGE+255)/256, 256, 0, stream>>>(dstp, DEG0, NEDGE);
  dis_kernel<<<(NTOK+255)/256, 256, 0, stream>>>(DEG0, DIS0, NTOK);
  coef0_kernel<<<(NEDGE+255)/256, 256, 0, stream>>>(srcp, dstp, DIS0, COEF0);
  zero_f_kernel<<<(MG*4096+255)/256, 256, 0, stream>>>(AG0, MG*4096);
  diagA_kernel<<<MG, 64, 0, stream>>>(DIS0, AG0, NNODE);
  edgeA_kernel<<<(NEDGE+255)/256, 256, 0, stream>>>(srcp, dstp, COEF0, AG0, NNODE);
  gemm_kernel<<<dim3(8,8), 256, 0, stream>>>(W_emb1, conv1_W, WCf, 512, 512, NNODE);
  gcnT_kernel<<<256, 256, 0, stream>>>(WCf, convs_W, CTh, CTl, CVh, CVl);

  // ---- transformer encoder ----
  for (int l = 0; l < NLAYER; ++l) {
    size_t oq = (size_t)l*1536*512, oo = (size_t)l*512*512;
    size_t o1 = (size_t)l*2048*512, o2 = (size_t)l*512*2048;
    gemm3_kernel<false,2><<<dim3(6,62,1), 256, 0, stream>>>(Th, Tl, WQh+oq, WQl+oq,
        bqkv + (size_t)l*3*DD, QKVf, nullptr, nullptr, 3*DD, 3*DD, DD, DD);
    attn_kernel<<<MG*NH, 256, 0, stream>>>(QKVf, ATh, ATl);
    gemm3_kernel<false,0><<<dim3(2,62,2), 256, 0, stream>>>(ATh, ATl, WOh+oo, WOl+oo,
        bo + (size_t)l*DD, PART, nullptr, nullptr, DD, DD, DD, 256);
    add_ln_kernel<<<NTOK, 256, 0, stream>>>(Th, Tl, PART, 2,
        g1 + (size_t)l*DD, be1 + (size_t)l*DD);
    gemm3_kernel<true,1><<<dim3(8,62,1), 256, 0, stream>>>(Th, Tl, W1h+o1, W1l+o1,
        b1 + (size_t)l*DFF, nullptr, BIGh, BIGl, DFF, DFF, DD, DD);
    gemm3_kernel<false,0><<<dim3(2,62,2), 256, 0, stream>>>(BIGh, BIGl, W2h+o2, W2l+o2,
        b2 + (size_t)l*DD, PART, nullptr, nullptr, DD, DD, DFF, 1024);
    add_ln_kernel<<<NTOK, 256, 0, stream>>>(Th, Tl, PART, 2,
        g2 + (size_t)l*DD, be2 + (size_t)l*DD);
  }

  // ---- conv1 = relu(A~0 @ (t @ Wcomb) + b) ----
  gemm3_kernel<false,0><<<dim3(2,62,2), 256, 0, stream>>>(Th, Tl, CTh, CTl,
      nullptr, PA, nullptr, nullptr, DD, DD, DD, 256);
  dense_agg_kernel<<<MG*8, 256, 0, stream>>>(AG0, PA, 2, MN, conv1_b,
      PA, NNODE, 1, nullptr, nullptr);

  // ---- SAGPool 1 ----
  gemv_kernel<<<(NTOK+3)/4, 256, 0, stream>>>(PA, pool1_W, HS, NTOK);
  dense_score_kernel<<<MG, 64, 0, stream>>>(AG0, HS, pool1_b, SC, NNODE);
  topk_kernel<<<MG, 64, 0, stream>>>(SC, PERM1, NNODE, KP1);
  gather_kernel<<<MG*KP1, 256, 0, stream>>>(PA, SC, PERM1, PA + MN, Hh, Hl, NNODE, KP1);
  readout_kernel<<<MG, 256, 0, stream>>>(PA + MN, Z, KP1, 0);

  // ---- filter_adj + dense adjacency level 1 ----
  fill_int_kernel<<<(NTOK+255)/256, 256, 0, stream>>>(NMAP, -1, NTOK);
  nmap_scatter_kernel<<<(MG*KP1+255)/256, 256, 0, stream>>>(PERM1, NMAP);
  fill_int_kernel<<<(MG*KP1+255)/256, 256, 0, stream>>>(DEG1, 1, MG*KP1);
  filter_kernel<<<(NEDGE+255)/256, 256, 0, stream>>>(srcp, dstp, NMAP, ES1, ED1, KEEP1, DEG1);
  dis_kernel<<<(MG*KP1+255)/256, 256, 0, stream>>>(DEG1, DIS1, MG*KP1);
  coef1_kernel<<<(NEDGE+255)/256, 256, 0, stream>>>(ES1, ED1, KEEP1, DIS1, COEF1);
  zero_f_kernel<<<(MG*4096+255)/256, 256, 0, stream>>>(AG1, MG*4096);
  diagA_kernel<<<MG, 64, 0, stream>>>(DIS1, AG1, KP1);
  edgeA_kernel<<<(NEDGE+255)/256, 256, 0, stream>>>(ES1, ED1, COEF1, AG1, KP1);

  // ---- 3 GCN layers on pooled graph ----
  const size_t MNP = (size_t)MG*KP1*DD;
  float* bases[3] = { PB, PA, PB };
  float* hfin = nullptr;
  for (int l = 0; l < NLAYER-1; ++l) {
    float* Pb = bases[l];
    gemm3_kernel<false,0><<<dim3(2,50,2), 256, 0, stream>>>(Hh, Hl, CVh + (size_t)l*DD*DD,
        CVl + (size_t)l*DD*DD, nullptr, Pb, nullptr, nullptr, DD, DD, DD, 256);
    dense_agg_kernel<<<MG*8, 256, 0, stream>>>(AG1, Pb, 2, MNP, convs_b + (size_t)l*DD,
        Pb, KP1, 1, (l < NLAYER-2) ? Hh : nullptr, (l < NLAYER-2) ? Hl : nullptr);
    hfin = Pb;
  }

  // ---- SAGPool 2 ----
  gemv_kernel<<<(MG*KP1+3)/4, 256, 0, stream>>>(hfin, pool2_W, HS, MG*KP1);
  dense_score_kernel<<<MG, 64, 0, stream>>>(AG1, HS, pool2_b, SC, KP1);
  topk_kernel<<<MG, 64, 0, stream>>>(SC, PERM2, KP1, KP2);
  gather_kernel<<<MG*KP2, 256, 0, stream>>>(hfin, SC, PERM2, PA, nullptr, nullptr, KP1, KP2);
  readout_kernel<<<MG, 256, 0, stream>>>(PA, Z, KP2, 1);

  // ---- MLP head ----
  mlp1_kernel<<<MG*4, 256, 0, stream>>>(Z, fc1_W, Pm);
  mlp2_kernel<<<MG, 256, 0, stream>>>(Pm, fc1_b, fc2_W, fc2_b, fc3_W, fc3_b, (float*)d_out);
}

// Round 13
// 1616.536 us; speedup vs baseline: 1.2677x; 1.2677x over previous
//
#include <hip/hip_runtime.h>
#include <float.h>
#include <math.h>

#define MG 128
#define NNODE 62
#define DD 512
#define NH 8
#define DH 64
#define DFF 2048
#define NLAYER 4
#define EPG 600
#define KP1 50
#define KP2 40
#define NTOK (MG*NNODE)      // 7936
#define NEDGE (MG*EPG)       // 76800
#define EPSV 1e-5f
#define PW 68                // padded fp32 LDS row width for attn

typedef unsigned short u16;
using bf16x8 = __attribute__((ext_vector_type(8))) short;
using f32x4  = __attribute__((ext_vector_type(4))) float;

__device__ __forceinline__ float wave_sum(float v) {
  for (int off = 32; off; off >>= 1) v += __shfl_xor(v, off);
  return v;
}
__device__ __forceinline__ float wave_max(float v) {
  for (int off = 32; off; off >>= 1) v = fmaxf(v, __shfl_xor(v, off));
  return v;
}
__device__ __forceinline__ u16 f2b(float x) {
  union { float f; unsigned u; } v; v.f = x;
  unsigned r = v.u + 0x7fffu + ((v.u >> 16) & 1u);
  return (u16)(r >> 16);
}
__device__ __forceinline__ float b2f(u16 h) {
  union { float f; unsigned u; } v; v.u = ((unsigned)h) << 16;
  return v.f;
}
__device__ __forceinline__ void f2bsplit(float x, u16& h, u16& l) {
  h = f2b(x);
  l = f2b(x - b2f(h));
}
__device__ __forceinline__ void load_lds16(const u16* g, u16* l) {
  __builtin_amdgcn_global_load_lds(
      (const __attribute__((address_space(1))) unsigned int*)(const void*)g,
      (__attribute__((address_space(3))) unsigned int*)(void*)l, 16, 0, 0);
}
__device__ __forceinline__ void cvt8(const float* __restrict__ p, bf16x8& vh, bf16x8& vl) {
  #pragma unroll
  for (int e = 0; e < 8; ++e) {
    u16 h, l; f2bsplit(p[e], h, l);
    vh[e] = (short)h; vl[e] = (short)l;
  }
}
__device__ __forceinline__ void cvt8s(const float* __restrict__ p, bf16x8& vh, bf16x8& vl) {
  #pragma unroll
  for (int e = 0; e < 8; ++e) {
    u16 h, l; f2bsplit(p[e*PW], h, l);
    vh[e] = (short)h; vl[e] = (short)l;
  }
}

// ---------------- BatchNorm stats ----------------
__global__ __launch_bounds__(256) void bn_stats_kernel(const float* __restrict__ x,
    float* __restrict__ mu, float* __restrict__ rs) {
  int s = blockIdx.x;
  float sum = 0.f, sq = 0.f;
  for (int i = threadIdx.x; i < MG*NNODE; i += 256) {
    int b = i / NNODE, j = i - b*NNODE;
    float v = x[(size_t)(b*NNODE + s)*NNODE + j];
    sum += v; sq += v*v;
  }
  __shared__ float r1[4], r2[4];
  sum = wave_sum(sum); sq = wave_sum(sq);
  int wv = threadIdx.x >> 6, lane = threadIdx.x & 63;
  if (lane == 0) { r1[wv] = sum; r2[wv] = sq; }
  __syncthreads();
  if (threadIdx.x == 0) {
    float S = r1[0]+r1[1]+r1[2]+r1[3];
    float Q = r2[0]+r2[1]+r2[2]+r2[3];
    float m = S / (float)(MG*NNODE);
    float var = Q / (float)(MG*NNODE) - m*m;
    mu[s] = m;
    rs[s] = rsqrtf(var + EPSV);
  }
}

// ---------------- embed: split-bf16 only ----------------
__global__ __launch_bounds__(256) void embed_kernel(const float* __restrict__ x,
    const float* __restrict__ mu, const float* __restrict__ rs,
    const float* __restrict__ gg, const float* __restrict__ bb,
    const float* __restrict__ W,
    u16* __restrict__ Th, u16* __restrict__ Tl) {
  int tok = blockIdx.x;
  int s = tok >> 7, b = tok & 127;
  __shared__ float xb[NNODE];
  if (threadIdx.x < NNODE) {
    float v = x[(size_t)(b*NNODE + s)*NNODE + threadIdx.x];
    xb[threadIdx.x] = (v - mu[s]) * rs[s] * gg[s] + bb[s];
  }
  __syncthreads();
  int d = threadIdx.x;
  float a0 = 0.f, a1 = 0.f;
  for (int j = 0; j < NNODE; ++j) {
    float xv = xb[j];
    a0 += xv * W[(size_t)j*DD + d];
    a1 += xv * W[(size_t)j*DD + d + 256];
  }
  size_t o = (size_t)tok*DD + d;
  u16 h, l;
  f2bsplit(a0, h, l); Th[o] = h; Tl[o] = l;
  f2bsplit(a1, h, l); Th[o+256] = h; Tl[o+256] = l;
}

// ---------------- fp32 GEMM (only for Wcomb = W_emb1 @ conv1_W) ----------------
__global__ __launch_bounds__(256) void gemm_kernel(const float* __restrict__ A,
    const float* __restrict__ B, float* __restrict__ C, int M, int N, int K) {
  __shared__ float As[16][68];
  __shared__ float Bs[16][68];
  int bm = blockIdx.y * 64, bn = blockIdx.x * 64;
  int tid = threadIdx.x;
  int tx = tid & 15, ty = tid >> 4;
  float acc[4][4] = {};
  for (int k0 = 0; k0 < K; k0 += 16) {
    {
      int row = tid >> 2; int kk = (tid & 3) * 4;
      int gm = bm + row;
      #pragma unroll
      for (int i = 0; i < 4; ++i) {
        int gk = k0 + kk + i;
        As[kk+i][row] = (gm < M && gk < K) ? A[(size_t)gm*K + gk] : 0.f;
      }
    }
    {
      int krow = tid >> 4; int nn = (tid & 15) * 4;
      int gk = k0 + krow;
      #pragma unroll
      for (int i = 0; i < 4; ++i) {
        int gn = bn + nn + i;
        Bs[krow][nn+i] = (gk < K && gn < N) ? B[(size_t)gk*N + gn] : 0.f;
      }
    }
    __syncthreads();
    #pragma unroll
    for (int k = 0; k < 16; ++k) {
      float a[4], bb2[4];
      #pragma unroll
      for (int i = 0; i < 4; ++i) a[i] = As[k][ty*4+i];
      #pragma unroll
      for (int j = 0; j < 4; ++j) bb2[j] = Bs[k][tx*4+j];
      #pragma unroll
      for (int i = 0; i < 4; ++i)
        #pragma unroll
        for (int j = 0; j < 4; ++j) acc[i][j] += a[i]*bb2[j];
    }
    __syncthreads();
  }
  #pragma unroll
  for (int i = 0; i < 4; ++i) {
    int gm = bm + ty*4 + i;
    if (gm >= M) continue;
    #pragma unroll
    for (int j = 0; j < 4; ++j) {
      int gn = bn + tx*4 + j;
      if (gn >= N) continue;
      C[(size_t)gm*N + gn] = acc[i][j];
    }
  }
}

// ---------------- transpose+split tile helper ----------------
__device__ __forceinline__ void transpose_split_tile(const float* __restrict__ W,
    u16* __restrict__ th, u16* __restrict__ tl,
    int K, int N, int Kp, int bx, int by, float (*t)[65]) {
  int k0 = by*64, n0 = bx*64;
  for (int i = threadIdx.x; i < 64*64; i += 256) {
    int r = i >> 6, c = i & 63;
    int gk = k0 + r, gn = n0 + c;
    t[r][c] = (gk < K && gn < N) ? W[(size_t)gk*N + gn] : 0.f;
  }
  __syncthreads();
  for (int i = threadIdx.x; i < 64*64; i += 256) {
    int r = i >> 6, c = i & 63;
    int gn = n0 + r, gk = k0 + c;
    u16 h, l; f2bsplit(t[c][r], h, l);
    th[(size_t)gn*Kp + gk] = h;
    tl[(size_t)gn*Kp + gk] = l;
  }
}

// ---------------- ALL layers batched weight transpose ----------------
__global__ __launch_bounds__(256) void allT_kernel(
    const float* __restrict__ Wqkv, const float* __restrict__ Wo,
    const float* __restrict__ W1, const float* __restrict__ W2,
    u16* WQh, u16* WQl, u16* WOh, u16* WOl,
    u16* W1h, u16* W1l, u16* W2h, u16* W2l) {
  __shared__ float t[64][65];
  int layer = blockIdx.x / 768;
  int b = blockIdx.x % 768;
  const float* wqkv = Wqkv + (size_t)layer*DD*3*DD;
  const float* wo   = Wo   + (size_t)layer*DD*DD;
  const float* w1   = W1   + (size_t)layer*DD*DFF;
  const float* w2   = W2   + (size_t)layer*DFF*DD;
  size_t oq = (size_t)layer*1536*512, oo = (size_t)layer*512*512;
  size_t o1 = (size_t)layer*2048*512, o2 = (size_t)layer*512*2048;
  if (b < 192)      transpose_split_tile(wqkv, WQh+oq, WQl+oq, 512, 1536, 512, b % 24, b / 24, t);
  else if (b < 256) { int q = b - 192; transpose_split_tile(wo, WOh+oo, WOl+oo, 512, 512, 512, q % 8, q / 8, t); }
  else if (b < 512) { int q = b - 256; transpose_split_tile(w1, W1h+o1, W1l+o1, 512, 2048, 512, q % 32, q / 32, t); }
  else              { int q = b - 512; transpose_split_tile(w2, W2h+o2, W2l+o2, 2048, 512, 2048, q % 8, q / 8, t); }
}

// ---------------- GCN weights transpose (Wcomb, convs_W[0..2]) ----------------
__global__ __launch_bounds__(256) void gcnT_kernel(
    const float* __restrict__ WC, const float* __restrict__ convs_W,
    u16* CTh, u16* CTl, u16* CVh, u16* CVl) {
  __shared__ float t[64][65];
  int job = blockIdx.x >> 6, q = blockIdx.x & 63;
  int bx = q % 8, by = q / 8;
  if (job == 0) transpose_split_tile(WC, CTh, CTl, 512, 512, 512, bx, by, t);
  else {
    int l = job - 1;
    transpose_split_tile(convs_W + (size_t)l*DD*DD,
        CVh + (size_t)l*DD*DD, CVl + (size_t)l*DD*DD, 512, 512, 512, bx, by, t);
  }
}

// ---------------- split-bf16 MFMA GEMM: counted-vmcnt 2-phase, 128x128 tile ----------------
// OUTMODE: 0 fp32 [M][Nstride]; 1 split-bf16 linear; 2 fp32 attn tiles.
template<bool RELU, int OUTMODE>
__global__ __launch_bounds__(256) void gemm3_kernel(
    const u16* __restrict__ Ah, const u16* __restrict__ Al,
    const u16* __restrict__ Bh, const u16* __restrict__ Bl,
    const float* __restrict__ bias,
    float* __restrict__ Cf, u16* __restrict__ Ch, u16* __restrict__ Cl,
    int Nreal, int Nstride, int Kp, int KC) {
  __shared__ alignas(16) u16 sA[2][2][4096];
  __shared__ alignas(16) u16 sB[2][2][4096];
  unsigned nx = gridDim.x, ny = gridDim.y;
  unsigned nwg = nx * ny * gridDim.z;
  unsigned lb = blockIdx.x + nx*(blockIdx.y + ny*blockIdx.z);
  unsigned swz = lb;
  if ((nwg & 7u) == 0u) {
    unsigned cpx = nwg >> 3;
    swz = (lb & 7u)*cpx + (lb >> 3);
  }
  unsigned bxi = swz % nx;
  unsigned rem = swz / nx;
  unsigned byi = rem % ny;
  unsigned bzi = rem / ny;
  int bm = byi * 128, bn = bxi * 128;
  int z = bzi;
  int tid = threadIdx.x;
  int wv = tid >> 6, lane = tid & 63;
  int wr = (wv >> 1) * 64, wc = (wv & 1) * 64;
  f32x4 acc[4][4];
  #pragma unroll
  for (int i = 0; i < 4; ++i)
    #pragma unroll
    for (int j = 0; j < 4; ++j) acc[i][j] = (f32x4){0.f,0.f,0.f,0.f};

  int r0 = tid >> 2;
  int lin = (tid & 3) * 8;
  int c0 = lin ^ (((r0 >> 1) & 3) << 3);
  int r1 = r0 + 64;
  int c1 = lin ^ (((r1 >> 1) & 3) << 3);
  int fr = lane & 15, fo = (lane >> 4) * 8;

  int kbeg = z * KC;
  const u16* pA0 = Ah + (size_t)(bm + r0)*Kp + kbeg + c0;
  const u16* pA1 = Ah + (size_t)(bm + r1)*Kp + kbeg + c1;
  const u16* pB0 = Bh + (size_t)(bn + r0)*Kp + kbeg + c0;
  const u16* pB1 = Bh + (size_t)(bn + r1)*Kp + kbeg + c1;
  const ptrdiff_t dA = Al - Ah;
  const ptrdiff_t dB = Bl - Bh;

  auto stage = [&](int bi) {
    load_lds16(pA0,      &sA[bi][0][tid*8]);
    load_lds16(pA1,      &sA[bi][0][2048 + tid*8]);
    load_lds16(pA0 + dA, &sA[bi][1][tid*8]);
    load_lds16(pA1 + dA, &sA[bi][1][2048 + tid*8]);
    load_lds16(pB0,      &sB[bi][0][tid*8]);
    load_lds16(pB1,      &sB[bi][0][2048 + tid*8]);
    load_lds16(pB0 + dB, &sB[bi][1][tid*8]);
    load_lds16(pB1 + dB, &sB[bi][1][2048 + tid*8]);
    pA0 += 32; pA1 += 32; pB0 += 32; pB1 += 32;
  };

  int nk = KC >> 5;
  stage(0);
  int cur = 0;
  for (int t = 0; t < nk; ++t) {
    if (t + 1 < nk) {
      stage(cur ^ 1);
      asm volatile("s_waitcnt vmcnt(8)" ::: "memory");
    } else {
      asm volatile("s_waitcnt vmcnt(0)" ::: "memory");
    }
    __builtin_amdgcn_s_barrier();
    __builtin_amdgcn_sched_barrier(0);
    bf16x8 ah[4], al[4], bh[4], bl[4];
    #pragma unroll
    for (int i = 0; i < 4; ++i) {
      int ra = wr + i*16 + fr;
      int ea = ra*32 + (fo ^ (((ra >> 1) & 3) << 3));
      ah[i] = *(const bf16x8*)&sA[cur][0][ea];
      al[i] = *(const bf16x8*)&sA[cur][1][ea];
      int rb = wc + i*16 + fr;
      int eb = rb*32 + (fo ^ (((rb >> 1) & 3) << 3));
      bh[i] = *(const bf16x8*)&sB[cur][0][eb];
      bl[i] = *(const bf16x8*)&sB[cur][1][eb];
    }
    #pragma unroll
    for (int i = 0; i < 4; ++i)
      #pragma unroll
      for (int j = 0; j < 4; ++j) {
        acc[i][j] = __builtin_amdgcn_mfma_f32_16x16x32_bf16(ah[i], bh[j], acc[i][j], 0, 0, 0);
        acc[i][j] = __builtin_amdgcn_mfma_f32_16x16x32_bf16(ah[i], bl[j], acc[i][j], 0, 0, 0);
        acc[i][j] = __builtin_amdgcn_mfma_f32_16x16x32_bf16(al[i], bh[j], acc[i][j], 0, 0, 0);
      }
    __builtin_amdgcn_s_barrier();
    cur ^= 1;
  }
  size_t pstride = (size_t)gridDim.y * 128 * Nstride;
  int cr = (lane >> 4) * 4, cc = lane & 15;
  #pragma unroll
  for (int i = 0; i < 4; ++i) {
    #pragma unroll
    for (int j = 0; j < 4; ++j) {
      int gn = bn + wc + j*16 + cc;
      if (gn >= Nstride) continue;
      #pragma unroll
      for (int q = 0; q < 4; ++q) {
        int gm = bm + wr + i*16 + cr + q;
        float v = acc[i][j][q];
        if (gn < Nreal) { if (bias && z == 0) v += bias[gn]; } else v = 0.f;
        if (RELU) v = fmaxf(v, 0.f);
        if (OUTMODE == 0) {
          Cf[(size_t)z*pstride + (size_t)gm*Nstride + gn] = v;
        } else if (OUTMODE == 1) {
          size_t o = (size_t)z*pstride + (size_t)gm*Nstride + gn;
          u16 h, l; f2bsplit(v, h, l);
          Ch[o] = h; Cl[o] = l;
        } else {
          int which = gn >> 9, hh2 = (gn >> 6) & 7, d = gn & 63;
          int b2 = gm & 127, s2 = gm >> 7;
          Cf[(size_t)((which*NH + hh2)*MG + b2)*4096 + s2*64 + d] = v;
        }
      }
    }
  }
}

// ---------------- MFMA attention per (b,h): fp32 in, in-register split-bf16 ----------------
__global__ __launch_bounds__(256) void attn_kernel(const float* __restrict__ QKV,
    u16* __restrict__ Oh, u16* __restrict__ Ol) {
  int b = blockIdx.x >> 3, h = blockIdx.x & 7;
  __shared__ float sQ[64*PW];
  __shared__ float sK[64*PW];
  __shared__ float sV[64*PW];
  u16* sPh = (u16*)sK;
  u16* sPl = ((u16*)sK) + 4096;
  float* Ss = sQ;
  int tid = threadIdx.x, wv = tid >> 6, lane = tid & 63;
  int fr = lane & 15, fq = lane >> 4;
  size_t base0 = (size_t)(h*MG + b)*4096;
  const float* Qg = QKV + base0;
  const float* Kg = QKV + (size_t)NH*MG*4096 + base0;
  const float* Vg = QKV + (size_t)2*NH*MG*4096 + base0;
  #pragma unroll
  for (int i = 0; i < 4; ++i) {
    int c = tid + i*256;
    int r = c >> 4, col = (c & 15) * 4;
    f32x4 q4 = *(const f32x4*)(Qg + (size_t)c*4);
    f32x4 k4 = *(const f32x4*)(Kg + (size_t)c*4);
    f32x4 v4 = *(const f32x4*)(Vg + (size_t)c*4);
    *(f32x4*)&sQ[r*PW + col] = q4;
    *(f32x4*)&sK[r*PW + col] = k4;
    *(f32x4*)&sV[r*PW + col] = v4;
  }
  if (tid < 128) sV[(62 + (tid >> 6))*PW + (tid & 63)] = 0.f;
  __syncthreads();
  int rA = 16*wv + fr;
  bf16x8 qh[2], ql[2];
  #pragma unroll
  for (int kk = 0; kk < 2; ++kk)
    cvt8(&sQ[rA*PW + 32*kk + 8*fq], qh[kk], ql[kk]);
  __syncthreads();
  // ---- QK^T ----
  f32x4 accS[4];
  #pragma unroll
  for (int j = 0; j < 4; ++j) accS[j] = (f32x4){0.f,0.f,0.f,0.f};
  __builtin_amdgcn_s_setprio(1);
  #pragma unroll
  for (int kk = 0; kk < 2; ++kk) {
    #pragma unroll
    for (int j = 0; j < 4; ++j) {
      int rB = 16*j + fr;
      bf16x8 kh, kl;
      cvt8(&sK[rB*PW + 32*kk + 8*fq], kh, kl);
      accS[j] = __builtin_amdgcn_mfma_f32_16x16x32_bf16(qh[kk], kh, accS[j], 0, 0, 0);
      accS[j] = __builtin_amdgcn_mfma_f32_16x16x32_bf16(qh[kk], kl, accS[j], 0, 0, 0);
      accS[j] = __builtin_amdgcn_mfma_f32_16x16x32_bf16(ql[kk], kh, accS[j], 0, 0, 0);
    }
  }
  __builtin_amdgcn_s_setprio(0);
  #pragma unroll
  for (int j = 0; j < 4; ++j)
    #pragma unroll
    for (int q = 0; q < 4; ++q)
      Ss[(16*wv + fq*4 + q)*PW + 16*j + fr] = accS[j][q];
  __syncthreads();
  // ---- softmax ----
  for (int rr = 0; rr < 16; ++rr) {
    int row = 16*wv + rr;
    float sv = (lane < NNODE) ? Ss[row*PW + lane]*0.125f : -FLT_MAX;
    float mx = wave_max(sv);
    float e = (lane < NNODE) ? expf(sv - mx) : 0.f;
    float sm = wave_sum(e);
    float p = e / sm;
    u16 ph, pl; f2bsplit(p, ph, pl);
    int pos = row*64 + ((((lane >> 3) ^ (row & 7)) << 3) | (lane & 7));
    sPh[pos] = ph; sPl[pos] = pl;
  }
  __syncthreads();
  // ---- PV ----
  f32x4 accO[4];
  #pragma unroll
  for (int j = 0; j < 4; ++j) accO[j] = (f32x4){0.f,0.f,0.f,0.f};
  __builtin_amdgcn_s_setprio(1);
  #pragma unroll
  for (int kk = 0; kk < 2; ++kk) {
    int cha = (((4*kk + fq) ^ (rA & 7)) << 3);
    bf16x8 pah = *(const bf16x8*)&sPh[rA*64 + cha];
    bf16x8 pal = *(const bf16x8*)&sPl[rA*64 + cha];
    #pragma unroll
    for (int j = 0; j < 4; ++j) {
      bf16x8 vh, vl;
      cvt8s(&sV[(32*kk + 8*fq)*PW + 16*j + fr], vh, vl);
      accO[j] = __builtin_amdgcn_mfma_f32_16x16x32_bf16(pah, vh, accO[j], 0, 0, 0);
      accO[j] = __builtin_amdgcn_mfma_f32_16x16x32_bf16(pah, vl, accO[j], 0, 0, 0);
      accO[j] = __builtin_amdgcn_mfma_f32_16x16x32_bf16(pal, vh, accO[j], 0, 0, 0);
    }
  }
  __builtin_amdgcn_s_setprio(0);
  #pragma unroll
  for (int j = 0; j < 4; ++j) {
    #pragma unroll
    for (int q = 0; q < 4; ++q) {
      int s2 = 16*wv + fq*4 + q;
      if (s2 < NNODE) {
        int d = 16*j + fr;
        size_t o = ((size_t)(s2*MG + b))*DD + h*DH + d;
        u16 hh2, ll2; f2bsplit(accO[j][q], hh2, ll2);
        Oh[o] = hh2; Ol[o] = ll2;
      }
    }
  }
}

// ---------------- LayerNorm(residual(split) + sum_z PART[z]) -> split ----------------
__global__ __launch_bounds__(256) void add_ln_kernel(
    u16* __restrict__ Xh, u16* __restrict__ Xl,
    const float* __restrict__ P, int nchunk,
    const float* __restrict__ gg, const float* __restrict__ bb) {
  size_t row = blockIdx.x;
  int t = threadIdx.x;
  const size_t MN = (size_t)NTOK*DD;
  float r0 = 0.f, r1 = 0.f;
  for (int z = 0; z < nchunk; ++z) {
    r0 += P[z*MN + row*DD + t];
    r1 += P[z*MN + row*DD + t + 256];
  }
  float v0 = b2f(Xh[row*DD + t]) + b2f(Xl[row*DD + t]) + r0;
  float v1 = b2f(Xh[row*DD + t + 256]) + b2f(Xl[row*DD + t + 256]) + r1;
  __shared__ float red[4];
  float s = wave_sum(v0 + v1);
  int wv = t >> 6, lane = t & 63;
  if (lane == 0) red[wv] = s;
  __syncthreads();
  float mu = (red[0]+red[1]+red[2]+red[3]) * (1.f/DD);
  float d0 = v0 - mu, d1 = v1 - mu;
  float q = wave_sum(d0*d0 + d1*d1);
  __syncthreads();
  if (lane == 0) red[wv] = q;
  __syncthreads();
  float var = (red[0]+red[1]+red[2]+red[3]) * (1.f/DD);
  float rs = rsqrtf(var + EPSV);
  float o0 = d0*rs*gg[t] + bb[t];
  float o1 = d1*rs*gg[t+256] + bb[t+256];
  u16 h, l;
  f2bsplit(o0, h, l); Xh[row*DD + t] = h; Xl[row*DD + t] = l;
  f2bsplit(o1, h, l); Xh[row*DD + t+256] = h; Xl[row*DD + t+256] = l;
}

// ---------------- graph-structure helpers ----------------
__global__ void fill_int_kernel(int* p, int v, int n) {
  int i = blockIdx.x*256 + threadIdx.x;
  if (i < n) p[i] = v;
}
__global__ void zero_f_kernel(float* p, int n) {
  int i = blockIdx.x*256 + threadIdx.x;
  if (i < n) p[i] = 0.f;
}
__global__ void count_deg_kernel(const int* __restrict__ dst, int* deg, int n) {
  int e = blockIdx.x*256 + threadIdx.x;
  if (e < n) atomicAdd(&deg[dst[e]], 1);
}
__global__ void dis_kernel(const int* __restrict__ deg, float* dis, int n) {
  int i = blockIdx.x*256+threadIdx.x;
  if (i < n) dis[i] = rsqrtf((float)deg[i]);
}
__global__ void coef0_kernel(const int* __restrict__ src, const int* __restrict__ dst,
                             const float* __restrict__ dis, float* coef) {
  int e = blockIdx.x*256+threadIdx.x;
  if (e < NEDGE) coef[e] = dis[src[e]]*dis[dst[e]];
}
__global__ void coef1_kernel(const int* __restrict__ src, const int* __restrict__ dst,
                             const int* __restrict__ keep,
                             const float* __restrict__ dis, float* coef) {
  int e = blockIdx.x*256+threadIdx.x;
  if (e < NEDGE) coef[e] = keep[e] ? dis[src[e]]*dis[dst[e]] : 0.f;
}

// ---------------- dense per-graph normalized adjacency build ----------------
__global__ __launch_bounds__(64) void diagA_kernel(const float* __restrict__ dis,
    float* __restrict__ AG, int NP) {
  int g = blockIdx.x, lane = threadIdx.x;
  if (lane < NP) {
    float d = dis[g*NP + lane];
    AG[(size_t)g*4096 + lane*64 + lane] = d*d;
  }
}
__global__ __launch_bounds__(256) void edgeA_kernel(const int* __restrict__ src,
    const int* __restrict__ dst, const float* __restrict__ coef,
    float* __restrict__ AG, int NP) {
  int e = blockIdx.x*256 + threadIdx.x;
  if (e >= NEDGE) return;
  float c = coef[e];
  if (c == 0.f) return;
  int g = e / EPG;
  int ls = src[e] - g*NP, ld = dst[e] - g*NP;
  atomicAdd(&AG[(size_t)g*4096 + ld*64 + ls], c);
}

// ---------------- dense GCN aggregation ----------------
__global__ __launch_bounds__(256) void dense_agg_kernel(
    const float* __restrict__ AG,
    const float* __restrict__ P, int nchunk, size_t mn,
    const float* __restrict__ bias,
    float* __restrict__ Hout, int NP, int relu,
    u16* __restrict__ outh, u16* __restrict__ outl) {
  int g = blockIdx.x >> 3;
  int ct = (blockIdx.x & 7) * 64;
  __shared__ float hls[64*64];
  __shared__ float At[64*68];
  int base = g * NP;
  for (int idx = threadIdx.x; idx < 64*64; idx += 256) {
    int r = idx >> 6, c = idx & 63;
    float v = 0.f;
    if (r < NP) {
      for (int z = 0; z < nchunk; ++z)
        v += P[z*mn + (size_t)(base+r)*DD + ct + c];
    }
    hls[idx] = v;
    At[c*68 + r] = AG[(size_t)g*4096 + idx];
  }
  __syncthreads();
  int wv = threadIdx.x >> 6, lane = threadIdx.x & 63;
  int i0 = wv * 16;
  f32x4 acc[4];
  #pragma unroll
  for (int q = 0; q < 4; ++q) acc[q] = (f32x4){0.f,0.f,0.f,0.f};
  for (int j = 0; j < NP; ++j) {
    float hv = hls[j*64 + lane];
    const f32x4* ap = (const f32x4*)&At[j*68 + i0];
    f32x4 a0 = ap[0], a1 = ap[1], a2 = ap[2], a3 = ap[3];
    #pragma unroll
    for (int t = 0; t < 4; ++t) {
      acc[0][t] += a0[t] * hv;
      acc[1][t] += a1[t] * hv;
      acc[2][t] += a2[t] * hv;
      acc[3][t] += a3[t] * hv;
    }
  }
  float bv = bias[ct + lane];
  #pragma unroll
  for (int q = 0; q < 4; ++q) {
    #pragma unroll
    for (int t = 0; t < 4; ++t) {
      int i = i0 + q*4 + t;
      if (i < NP) {
        float v = acc[q][t] + bv;
        if (relu) v = fmaxf(v, 0.f);
        size_t o = (size_t)(base+i)*DD + ct + lane;
        Hout[o] = v;
        if (outh) { u16 h, l; f2bsplit(v, h, l); outh[o] = h; outl[o] = l; }
      }
    }
  }
}

// ---------------- dense SAGPool score ----------------
__global__ __launch_bounds__(64) void dense_score_kernel(
    const float* __restrict__ AG, const float* __restrict__ hsv,
    const float* __restrict__ pb, float* __restrict__ sc, int NP) {
  int g = blockIdx.x, lane = threadIdx.x;
  __shared__ float hls[64];
  __shared__ float At[64*65];
  hls[lane] = (lane < NP) ? hsv[g*NP + lane] : 0.f;
  for (int idx = lane; idx < 64*64; idx += 64) {
    int i = idx >> 6, j = idx & 63;
    At[j*65 + i] = AG[(size_t)g*4096 + idx];
  }
  __syncthreads();
  if (lane < NP) {
    float acc = 0.f;
    for (int j = 0; j < NP; ++j) acc += At[j*65 + lane] * hls[j];
    sc[g*NP + lane] = acc + pb[0];
  }
}

// ---------------- gemv ----------------
__global__ __launch_bounds__(256) void gemv_kernel(const float* __restrict__ h,
    const float* __restrict__ wv, float* __restrict__ out, int n) {
  int node = blockIdx.x*4 + (threadIdx.x >> 6);
  int lane = threadIdx.x & 63;
  if (node >= n) return;
  const float* row = h + (size_t)node*DD;
  float acc = 0.f;
  for (int d = lane; d < DD; d += 64) acc += row[d]*wv[d];
  acc = wave_sum(acc);
  if (lane == 0) out[node] = acc;
}

// ---------------- per-graph top-k ----------------
__global__ __launch_bounds__(64) void topk_kernel(const float* __restrict__ sc,
    int* __restrict__ perm, int NP, int KK) {
  int g = blockIdx.x, lane = threadIdx.x;
  float v = (lane < NP) ? sc[g*NP+lane] : -FLT_MAX;
  for (int r = 0; r < KK; ++r) {
    float bv = v; int bi = lane;
    for (int off = 32; off; off >>= 1) {
      float ov = __shfl_xor(bv, off);
      int oi = __shfl_xor(bi, off);
      if (ov > bv || (ov == bv && oi < bi)) { bv = ov; bi = oi; }
    }
    if (lane == 0) perm[g*KK + r] = bi;
    if (lane == bi) v = -FLT_MAX;
  }
}

// ---------------- gather pooled ----------------
__global__ __launch_bounds__(256) void gather_kernel(const float* __restrict__ h,
    const float* __restrict__ sc, const int* __restrict__ perm,
    float* __restrict__ xn, u16* __restrict__ outh, u16* __restrict__ outl,
    int NP, int KK) {
  int j = blockIdx.x;
  int g = j / KK;
  int pi = perm[j];
  float t = tanhf(sc[g*NP + pi]);
  const float* srow = h + (size_t)(g*NP + pi)*DD;
  size_t o = (size_t)j*DD + threadIdx.x;
  float v0 = srow[threadIdx.x]*t;
  float v1 = srow[threadIdx.x+256]*t;
  xn[o] = v0; xn[o+256] = v1;
  if (outh) {
    u16 hh, ll;
    f2bsplit(v0, hh, ll); outh[o] = hh; outl[o] = ll;
    f2bsplit(v1, hh, ll); outh[o+256] = hh; outl[o+256] = ll;
  }
}

__global__ void nmap_scatter_kernel(const int* __restrict__ perm, int* __restrict__ nmap) {
  int j = blockIdx.x*256 + threadIdx.x;
  if (j < MG*KP1) nmap[(j/KP1)*NNODE + perm[j]] = j;
}

__global__ void filter_kernel(const int* __restrict__ src0, const int* __restrict__ dst0,
    const int* __restrict__ nmap, int* __restrict__ es, int* __restrict__ ed,
    int* __restrict__ keep, int* __restrict__ deg1) {
  int e = blockIdx.x*256+threadIdx.x;
  if (e >= NEDGE) return;
  int ns = nmap[src0[e]], nd = nmap[dst0[e]];
  int k = (ns >= 0) && (nd >= 0);
  es[e] = k ? ns : 0;
  ed[e] = k ? nd : 0;
  keep[e] = k;
  if (k) atomicAdd(&deg1[nd], 1);
}

// ---------------- readout: gmp || gap ----------------
__global__ __launch_bounds__(256) void readout_kernel(const float* __restrict__ h,
    float* __restrict__ z, int KK, int acc) {
  int g = blockIdx.x;
  for (int c = threadIdx.x; c < DD; c += 256) {
    float mx = -FLT_MAX, sm = 0.f;
    for (int r = 0; r < KK; ++r) {
      float v = h[(size_t)(g*KK+r)*DD + c];
      mx = fmaxf(mx, v); sm += v;
    }
    float mean = sm / (float)KK;
    if (acc) { z[(size_t)g*1024 + c] += mx; z[(size_t)g*1024 + 512 + c] += mean; }
    else     { z[(size_t)g*1024 + c]  = mx; z[(size_t)g*1024 + 512 + c]  = mean; }
  }
}

// ---------------- MLP head stage 1 ----------------
__global__ __launch_bounds__(256) void mlp1_kernel(const float* __restrict__ Z,
    const float* __restrict__ W1, float* __restrict__ Pm) {
  int b = blockIdx.x;
  int g = b >> 2, zc = b & 3;
  __shared__ float z[256];
  int t = threadIdx.x;
  z[t] = Z[(size_t)g*1024 + zc*256 + t];
  __syncthreads();
  const float* Wb = W1 + (size_t)zc*256*512;
  float a0 = 0.f, a1 = 0.f;
  for (int k = 0; k < 256; ++k) {
    float zv = z[k];
    a0 += zv * Wb[(size_t)k*512 + t];
    a1 += zv * Wb[(size_t)k*512 + t + 256];
  }
  size_t o = ((size_t)zc*MG + g)*512;
  Pm[o + t] = a0;
  Pm[o + t + 256] = a1;
}

// ---------------- MLP head stage 2 ----------------
__global__ __launch_bounds__(256) void mlp2_kernel(const float* __restrict__ Pm,
    const float* __restrict__ b1,
    const float* __restrict__ W2, const float* __restrict__ b2,
    const float* __restrict__ W3, const float* __restrict__ b3,
    float* __restrict__ out) {
  int g = blockIdx.x;
  int t = threadIdx.x;
  int wv = t >> 6, lane = t & 63;
  __shared__ float h1[512];
  __shared__ float p2[4][256];
  __shared__ float h2[256];
  #pragma unroll
  for (int half = 0; half < 2; ++half) {
    int n = t + half*256;
    float a = b1[n];
    #pragma unroll
    for (int zc = 0; zc < 4; ++zc) a += Pm[((size_t)zc*MG + g)*512 + n];
    h1[n] = fmaxf(a, 0.f);
  }
  __syncthreads();
  {
    float a[4] = {0.f, 0.f, 0.f, 0.f};
    for (int k = wv*128; k < wv*128 + 128; ++k) {
      float hv = h1[k];
      #pragma unroll
      for (int q = 0; q < 4; ++q)
        a[q] += hv * W2[(size_t)k*256 + lane + q*64];
    }
    #pragma unroll
    for (int q = 0; q < 4; ++q) p2[wv][lane + q*64] = a[q];
  }
  __syncthreads();
  h2[t] = fmaxf(p2[0][t] + p2[1][t] + p2[2][t] + p2[3][t] + b2[t], 0.f);
  __syncthreads();
  if (wv < 2) {
    float acc = 0.f;
    for (int k = lane; k < 256; k += 64) acc += h2[k]*W3[(size_t)k*2 + wv];
    acc = wave_sum(acc);
    if (lane == 0) out[(size_t)g*2 + wv] = acc + b3[wv];
  }
}

extern "C" void kernel_launch(void* const* d_in, const int* in_sizes, int n_in,
                              void* d_out, int out_size, void* d_ws, size_t ws_size,
                              hipStream_t stream) {
  const float* x       = (const float*)d_in[0];
  const int*   edge    = (const int*)d_in[1];
  const float* bn_g    = (const float*)d_in[2];
  const float* bn_b    = (const float*)d_in[3];
  const float* W_emb   = (const float*)d_in[4];
  const float* Wqkv    = (const float*)d_in[5];
  const float* bqkv    = (const float*)d_in[6];
  const float* Wo      = (const float*)d_in[7];
  const float* bo      = (const float*)d_in[8];
  const float* W1      = (const float*)d_in[9];
  const float* b1      = (const float*)d_in[10];
  const float* W2      = (const float*)d_in[11];
  const float* b2      = (const float*)d_in[12];
  const float* g1      = (const float*)d_in[13];
  const float* be1     = (const float*)d_in[14];
  const float* g2      = (const float*)d_in[15];
  const float* be2     = (const float*)d_in[16];
  const float* W_emb1  = (const float*)d_in[17];
  const float* conv1_W = (const float*)d_in[18];
  const float* conv1_b = (const float*)d_in[19];
  const float* convs_W = (const float*)d_in[20];
  const float* convs_b = (const float*)d_in[21];
  const float* pool1_W = (const float*)d_in[22];
  const float* pool1_b = (const float*)d_in[23];
  const float* pool2_W = (const float*)d_in[24];
  const float* pool2_b = (const float*)d_in[25];
  const float* fc1_W   = (const float*)d_in[26];
  const float* fc1_b   = (const float*)d_in[27];
  const float* fc2_W   = (const float*)d_in[28];
  const float* fc2_b   = (const float*)d_in[29];
  const float* fc3_W   = (const float*)d_in[30];
  const float* fc3_b   = (const float*)d_in[31];
  (void)in_sizes; (void)n_in; (void)out_size; (void)ws_size;

  const int* srcp = edge;
  const int* dstp = edge + NEDGE;

  char* wsb = (char*)d_ws;
  size_t off = 0;
  auto alloc = [&](size_t bytes)->void* {
    void* p = wsb + off;
    off += (bytes + 255) & ~(size_t)255;
    return p;
  };
  const size_t MN = (size_t)NTOK*DD;
  size_t qkvB = (size_t)3*NH*MG*4096*4, ffnB = (size_t)NTOK*DFF*2*2;
  char* BIGU  = (char*)alloc(qkvB > ffnB ? qkvB : ffnB);
  u16* BIGh   = (u16*)BIGU;
  u16* BIGl   = BIGh + (size_t)NTOK*DFF;
  float* QKVf = (float*)BIGU;
  float* PART = (float*)alloc(4*MN*4);
  u16* Th   = (u16*)alloc(MN*2);
  u16* Tl   = (u16*)alloc(MN*2);
  u16* ATh  = (u16*)alloc(MN*2);
  u16* ATl  = (u16*)alloc(MN*2);
  u16* Hh   = (u16*)alloc((size_t)MG*KP1*DD*2);
  u16* Hl   = (u16*)alloc((size_t)MG*KP1*DD*2);
  u16* WQh  = (u16*)alloc((size_t)4*1536*512*2);
  u16* WQl  = (u16*)alloc((size_t)4*1536*512*2);
  u16* WOh  = (u16*)alloc((size_t)4*512*512*2);
  u16* WOl  = (u16*)alloc((size_t)4*512*512*2);
  u16* W1h  = (u16*)alloc((size_t)4*2048*512*2);
  u16* W1l  = (u16*)alloc((size_t)4*2048*512*2);
  u16* W2h  = (u16*)alloc((size_t)4*512*2048*2);
  u16* W2l  = (u16*)alloc((size_t)4*512*2048*2);
  float* WCf = (float*)alloc((size_t)512*512*4);
  u16* CTh  = (u16*)alloc((size_t)512*512*2);
  u16* CTl  = (u16*)alloc((size_t)512*512*2);
  u16* CVh  = (u16*)alloc((size_t)3*512*512*2);
  u16* CVl  = (u16*)alloc((size_t)3*512*512*2);
  float* AG0 = (float*)alloc((size_t)MG*4096*4);
  float* AG1 = (float*)alloc((size_t)MG*4096*4);
  float* MU   = (float*)alloc(NNODE*4);
  float* RS   = (float*)alloc(NNODE*4);
  int*   DEG0 = (int*)alloc(NTOK*4);
  float* DIS0 = (float*)alloc(NTOK*4);
  float* COEF0= (float*)alloc(NEDGE*4);
  float* HS   = (float*)alloc(NTOK*4);
  float* SC   = (float*)alloc(NTOK*4);
  int*   PERM1= (int*)alloc(MG*KP1*4);
  int*   NMAP = (int*)alloc(NTOK*4);
  int*   ES1  = (int*)alloc(NEDGE*4);
  int*   ED1  = (int*)alloc(NEDGE*4);
  int*   KEEP1= (int*)alloc(NEDGE*4);
  int*   DEG1 = (int*)alloc(MG*KP1*4);
  float* DIS1 = (float*)alloc(MG*KP1*4);
  float* COEF1= (float*)alloc(NEDGE*4);
  int*   PERM2= (int*)alloc(MG*KP2*4);
  float* Z    = (float*)alloc(MG*1024*4);
  float* Pm   = (float*)alloc((size_t)4*MG*512*4);

  float* PA = PART;
  float* PB = PART + 2*MN;

  // ---- prep ----
  bn_stats_kernel<<<NNODE, 256, 0, stream>>>(x, MU, RS);
  embed_kernel<<<NTOK, 256, 0, stream>>>(x, MU, RS, bn_g, bn_b, W_emb, Th, Tl);
  allT_kernel<<<4*768, 256, 0, stream>>>(Wqkv, Wo, W1, W2,
      WQh, WQl, WOh, WOl, W1h, W1l, W2h, W2l);
  fill_int_kernel<<<(NTOK+255)/256, 256, 0, stream>>>(DEG0, 1, NTOK);
  count_deg_kernel<<<(NEDGE+255)/256, 256, 0, stream>>>(dstp, DEG0, NEDGE);
  dis_kernel<<<(NTOK+255)/256, 256, 0, stream>>>(DEG0, DIS0, NTOK);
  coef0_kernel<<<(NEDGE+255)/256, 256, 0, stream>>>(srcp, dstp, DIS0, COEF0);
  zero_f_kernel<<<(MG*4096+255)/256, 256, 0, stream>>>(AG0, MG*4096);
  diagA_kernel<<<MG, 64, 0, stream>>>(DIS0, AG0, NNODE);
  edgeA_kernel<<<(NEDGE+255)/256, 256, 0, stream>>>(srcp, dstp, COEF0, AG0, NNODE);
  gemm_kernel<<<dim3(8,8), 256, 0, stream>>>(W_emb1, conv1_W, WCf, 512, 512, NNODE);
  gcnT_kernel<<<256, 256, 0, stream>>>(WCf, convs_W, CTh, CTl, CVh, CVl);

  // ---- transformer encoder ----
  for (int l = 0; l < NLAYER; ++l) {
    size_t oq = (size_t)l*1536*512, oo = (size_t)l*512*512;
    size_t o1 = (size_t)l*2048*512, o2 = (size_t)l*512*2048;
    gemm3_kernel<false,2><<<dim3(12,62,1), 256, 0, stream>>>(Th, Tl, WQh+oq, WQl+oq,
        bqkv + (size_t)l*3*DD, QKVf, nullptr, nullptr, 3*DD, 3*DD, DD, DD);
    attn_kernel<<<MG*NH, 256, 0, stream>>>(QKVf, ATh, ATl);
    gemm3_kernel<false,0><<<dim3(4,62,2), 256, 0, stream>>>(ATh, ATl, WOh+oo, WOl+oo,
        bo + (size_t)l*DD, PART, nullptr, nullptr, DD, DD, DD, 256);
    add_ln_kernel<<<NTOK, 256, 0, stream>>>(Th, Tl, PART, 2,
        g1 + (size_t)l*DD, be1 + (size_t)l*DD);
    gemm3_kernel<true,1><<<dim3(16,62,1), 256, 0, stream>>>(Th, Tl, W1h+o1, W1l+o1,
        b1 + (size_t)l*DFF, nullptr, BIGh, BIGl, DFF, DFF, DD, DD);
    gemm3_kernel<false,0><<<dim3(4,62,2), 256, 0, stream>>>(BIGh, BIGl, W2h+o2, W2l+o2,
        b2 + (size_t)l*DD, PART, nullptr, nullptr, DD, DD, DFF, 1024);
    add_ln_kernel<<<NTOK, 256, 0, stream>>>(Th, Tl, PART, 2,
        g2 + (size_t)l*DD, be2 + (size_t)l*DD);
  }

  // ---- conv1 = relu(A~0 @ (t @ Wcomb) + b) ----
  gemm3_kernel<false,0><<<dim3(4,62,2), 256, 0, stream>>>(Th, Tl, CTh, CTl,
      nullptr, PA, nullptr, nullptr, DD, DD, DD, 256);
  dense_agg_kernel<<<MG*8, 256, 0, stream>>>(AG0, PA, 2, MN, conv1_b,
      PA, NNODE, 1, nullptr, nullptr);

  // ---- SAGPool 1 ----
  gemv_kernel<<<(NTOK+3)/4, 256, 0, stream>>>(PA, pool1_W, HS, NTOK);
  dense_score_kernel<<<MG, 64, 0, stream>>>(AG0, HS, pool1_b, SC, NNODE);
  topk_kernel<<<MG, 64, 0, stream>>>(SC, PERM1, NNODE, KP1);
  gather_kernel<<<MG*KP1, 256, 0, stream>>>(PA, SC, PERM1, PA + MN, Hh, Hl, NNODE, KP1);
  readout_kernel<<<MG, 256, 0, stream>>>(PA + MN, Z, KP1, 0);

  // ---- filter_adj + dense adjacency level 1 ----
  fill_int_kernel<<<(NTOK+255)/256, 256, 0, stream>>>(NMAP, -1, NTOK);
  nmap_scatter_kernel<<<(MG*KP1+255)/256, 256, 0, stream>>>(PERM1, NMAP);
  fill_int_kernel<<<(MG*KP1+255)/256, 256, 0, stream>>>(DEG1, 1, MG*KP1);
  filter_kernel<<<(NEDGE+255)/256, 256, 0, stream>>>(srcp, dstp, NMAP, ES1, ED1, KEEP1, DEG1);
  dis_kernel<<<(MG*KP1+255)/256, 256, 0, stream>>>(DEG1, DIS1, MG*KP1);
  coef1_kernel<<<(NEDGE+255)/256, 256, 0, stream>>>(ES1, ED1, KEEP1, DIS1, COEF1);
  zero_f_kernel<<<(MG*4096+255)/256, 256, 0, stream>>>(AG1, MG*4096);
  diagA_kernel<<<MG, 64, 0, stream>>>(DIS1, AG1, KP1);
  edgeA_kernel<<<(NEDGE+255)/256, 256, 0, stream>>>(ES1, ED1, COEF1, AG1, KP1);

  // ---- 3 GCN layers on pooled graph ----
  const size_t MNP = (size_t)MG*KP1*DD;
  float* bases[3] = { PB, PA, PB };
  float* hfin = nullptr;
  for (int l = 0; l < NLAYER-1; ++l) {
    float* Pb = bases[l];
    gemm3_kernel<false,0><<<dim3(4,50,2), 256, 0, stream>>>(Hh, Hl, CVh + (size_t)l*DD*DD,
        CVl + (size_t)l*DD*DD, nullptr, Pb, nullptr, nullptr, DD, DD, DD, 256);
    dense_agg_kernel<<<MG*8, 256, 0, stream>>>(AG1, Pb, 2, MNP, convs_b + (size_t)l*DD,
        Pb, KP1, 1, (l < NLAYER-2) ? Hh : nullptr, (l < NLAYER-2) ? Hl : nullptr);
    hfin = Pb;
  }

  // ---- SAGPool 2 ----
  gemv_kernel<<<(MG*KP1+3)/4, 256, 0, stream>>>(hfin, pool2_W, HS, MG*KP1);
  dense_score_kernel<<<MG, 64, 0, stream>>>(AG1, HS, pool2_b, SC, KP1);
  topk_kernel<<<MG, 64, 0, stream>>>(SC, PERM2, KP1, KP2);
  gather_kernel<<<MG*KP2, 256, 0, stream>>>(hfin, SC, PERM2, PA, nullptr, nullptr, KP1, KP2);
  readout_kernel<<<MG, 256, 0, stream>>>(PA, Z, KP2, 1);

  // ---- MLP head ----
  mlp1_kernel<<<MG*4, 256, 0, stream>>>(Z, fc1_W, Pm);
  mlp2_kernel<<<MG, 256, 0, stream>>>(Pm, fc1_b, fc2_W, fc2_b, fc3_W, fc3_b, (float*)d_out);
}